// Round 5
// baseline (196.890 us; speedup 1.0000x reference)
//
#include <hip/hip_runtime.h>
#include <stdint.h>

typedef unsigned short u16;
typedef __attribute__((ext_vector_type(8))) short bf16x8;
typedef __attribute__((ext_vector_type(4))) float f32x4;

// ---------- helpers ----------
__device__ __forceinline__ u16 f2bf(float f) {
  union { float f; unsigned u; } v; v.f = f;
  unsigned r = v.u + 0x7fffu + ((v.u >> 16) & 1u);  // round-to-nearest-even
  return (u16)(r >> 16);
}

__device__ __forceinline__ void async_copy16(u16* lds_dst, const u16* g_src) {
  __builtin_amdgcn_global_load_lds(
      (const __attribute__((address_space(1))) unsigned*)(g_src),
      (__attribute__((address_space(3))) unsigned*)(lds_dst),
      16, 0, 0);
}

#define MFMA16(a, b, c) __builtin_amdgcn_mfma_f32_16x16x32_bf16((a), (b), (c), 0, 0, 0)

// ---------- convert f32 -> bf16 (vectorized) ----------
__global__ void cvt_bf16_kernel(const float* __restrict__ in, u16* __restrict__ out, int n4) {
  int i = blockIdx.x * blockDim.x + threadIdx.x;
  int stride = gridDim.x * blockDim.x;
  for (; i < n4; i += stride) {
    float4 v = ((const float4*)in)[i];
    ushort4 o;
    o.x = f2bf(v.x); o.y = f2bf(v.y); o.z = f2bf(v.z); o.w = f2bf(v.w);
    ((ushort4*)out)[i] = o;
  }
}

// ---------- tiled transpose + convert: in [R][C] f32 -> out [C][R] bf16 ----------
__global__ void transpose_cvt_kernel(const float* __restrict__ in, u16* __restrict__ out,
                                     int R, int C) {
  __shared__ float tile[32][33];
  int bx = blockIdx.x * 32;
  int by = blockIdx.y * 32;
  int tx = threadIdx.x & 31, ty = threadIdx.x >> 5;
#pragma unroll
  for (int j = 0; j < 32; j += 8)
    tile[ty + j][tx] = in[(size_t)(by + ty + j) * C + bx + tx];
  __syncthreads();
#pragma unroll
  for (int j = 0; j < 32; j += 8)
    out[(size_t)(bx + ty + j) * R + by + tx] = f2bf(tile[tx][ty + j]);
}

// ---------- 256x256 8-phase GEMM: C = A[M][K=1024] * BT[N][K]^T ----------
// 512 thr = 8 waves (2M x 4N); wave tile 128x64; BK=64, 2 K-slices of 32.
// LDS 128KB: A/B x dbuf x half[128][64], XOR-swizzled (row&7)<<4 via
// pre-swizzled global source. Counted vmcnt(4) per K-tile (T4); setprio (T5).
// MODE 0: qkv scatter epilogue (q*0.125, k, vT bf16); MODE 1: f32 [M][N].
template<int MODE>
__global__ __launch_bounds__(512, 2)
void gemm256(const u16* __restrict__ A, const u16* __restrict__ BT,
             int N,
             u16* __restrict__ q_o, u16* __restrict__ k_o, u16* __restrict__ vt_o,
             float* __restrict__ f_o) {
  constexpr int K = 1024;
  constexpr int NT = K / 64;  // 16 K-tiles
  __shared__ u16 AsF[2 * 2 * 8192];  // [dbuf][half][128*64]
  __shared__ u16 BsF[2 * 2 * 8192];

  const int t = threadIdx.x;
  const int w = t >> 6, l = t & 63;
  const int lr = l & 15, g = l >> 4;
  const int wm = w >> 2, wn = w & 3;
  const int m0 = blockIdx.x * 256, n0 = blockIdx.y * 256;

  // staging geometry: thread t covers rows r, r+64 of a [128][64] half at
  // byte-seg (t&7)*16; source pre-swizzled so linear LDS dest lands swizzled
  const int r = t >> 3;
  const int sw = ((t & 7) * 16) ^ ((r & 7) << 4);
  const u16* pA0 = A + (size_t)(m0 + r) * K + (sw >> 1);
  const u16* pA1 = pA0 + (size_t)128 * K;
  const u16* pB0 = BT + (size_t)(n0 + r) * K + (sw >> 1);
  const u16* pB1 = pB0 + (size_t)128 * K;

#define STG(ptr, dstbase)                                            \
  do {                                                               \
    async_copy16((dstbase) + t * 8, (ptr));                          \
    async_copy16((dstbase) + 4096 + t * 8, (ptr) + (size_t)64 * K);  \
  } while (0)

  f32x4 acc[8][4] = {};

  // prologue: tile0 (A0,A1,B0,B1) + tile1 (A0,A1) = 12 loads
  STG(pA0, AsF);
  STG(pA1, AsF + 8192);
  STG(pB0, BsF);
  STG(pB1, BsF + 8192);
  STG(pA0 + 64, AsF + 2 * 8192);
  STG(pA1 + 64, AsF + 3 * 8192);
  asm volatile("s_waitcnt vmcnt(4)" ::: "memory");  // tile0 retired
  asm volatile("s_barrier" ::: "memory");

  const int brow0 = (wn & 1) * 64;
  for (int T = 0; T < NT; ++T) {
    const int b = T & 1;
    const u16* Ab = AsF + (b * 2 + wm) * 8192;
    const u16* Bb = BsF + (b * 2 + (wn >> 1)) * 8192;
    bf16x8 a03[4][2], a47[4][2], bb[4][2];

    // ---- phase 0: read a03+bb01, stage B0(T+1), MFMA q(mf0-3,nf0-1) ----
#pragma unroll
    for (int mf = 0; mf < 4; ++mf)
#pragma unroll
      for (int ks = 0; ks < 2; ++ks) {
        const int row = mf * 16 + lr;
        a03[mf][ks] = *(const bf16x8*)&Ab[row * 64 + (((ks * 64 + g * 16) ^ ((row & 7) << 4)) >> 1)];
      }
#pragma unroll
    for (int nf = 0; nf < 2; ++nf)
#pragma unroll
      for (int ks = 0; ks < 2; ++ks) {
        const int row = brow0 + nf * 16 + lr;
        bb[nf][ks] = *(const bf16x8*)&Bb[row * 64 + (((ks * 64 + g * 16) ^ ((row & 7) << 4)) >> 1)];
      }
    if (T < NT - 1) STG(pB0 + (T + 1) * 64, BsF + ((T + 1) & 1) * 2 * 8192);
    asm volatile("s_barrier" ::: "memory");
    __builtin_amdgcn_s_setprio(1);
#pragma unroll
    for (int mf = 0; mf < 4; ++mf)
#pragma unroll
      for (int nf = 0; nf < 2; ++nf) {
        acc[mf][nf] = MFMA16(a03[mf][0], bb[nf][0], acc[mf][nf]);
        acc[mf][nf] = MFMA16(a03[mf][1], bb[nf][1], acc[mf][nf]);
      }
    __builtin_amdgcn_s_setprio(0);
    asm volatile("s_barrier" ::: "memory");

    // ---- phase 1: read a47+bb23, stage B1(T+1), MFMA q(mf0-3,nf2-3) ----
#pragma unroll
    for (int mf = 0; mf < 4; ++mf)
#pragma unroll
      for (int ks = 0; ks < 2; ++ks) {
        const int row = 64 + mf * 16 + lr;
        a47[mf][ks] = *(const bf16x8*)&Ab[row * 64 + (((ks * 64 + g * 16) ^ ((row & 7) << 4)) >> 1)];
      }
#pragma unroll
    for (int nf = 2; nf < 4; ++nf)
#pragma unroll
      for (int ks = 0; ks < 2; ++ks) {
        const int row = brow0 + nf * 16 + lr;
        bb[nf][ks] = *(const bf16x8*)&Bb[row * 64 + (((ks * 64 + g * 16) ^ ((row & 7) << 4)) >> 1)];
      }
    if (T < NT - 1) STG(pB1 + (T + 1) * 64, BsF + (((T + 1) & 1) * 2 + 1) * 8192);
    asm volatile("s_barrier" ::: "memory");
    __builtin_amdgcn_s_setprio(1);
#pragma unroll
    for (int mf = 0; mf < 4; ++mf)
#pragma unroll
      for (int nf = 2; nf < 4; ++nf) {
        acc[mf][nf] = MFMA16(a03[mf][0], bb[nf][0], acc[mf][nf]);
        acc[mf][nf] = MFMA16(a03[mf][1], bb[nf][1], acc[mf][nf]);
      }
    __builtin_amdgcn_s_setprio(0);
    asm volatile("s_waitcnt lgkmcnt(0)" ::: "memory");  // drain a47 before A-buf overwrite
    asm volatile("s_barrier" ::: "memory");

    // ---- phase 2: stage A0(T+2) into current buf, MFMA q(mf4-7,nf0-1) ----
    if (T < NT - 2) STG(pA0 + (T + 2) * 64, AsF + b * 2 * 8192);
    asm volatile("s_barrier" ::: "memory");
    __builtin_amdgcn_s_setprio(1);
#pragma unroll
    for (int mf = 0; mf < 4; ++mf)
#pragma unroll
      for (int nf = 0; nf < 2; ++nf) {
        acc[4 + mf][nf] = MFMA16(a47[mf][0], bb[nf][0], acc[4 + mf][nf]);
        acc[4 + mf][nf] = MFMA16(a47[mf][1], bb[nf][1], acc[4 + mf][nf]);
      }
    __builtin_amdgcn_s_setprio(0);
    asm volatile("s_barrier" ::: "memory");

    // ---- phase 3: stage A1(T+2), MFMA q(mf4-7,nf2-3), counted vmcnt ----
    if (T < NT - 2) STG(pA1 + (T + 2) * 64, AsF + (b * 2 + 1) * 8192);
    asm volatile("s_barrier" ::: "memory");
    __builtin_amdgcn_s_setprio(1);
#pragma unroll
    for (int mf = 0; mf < 4; ++mf)
#pragma unroll
      for (int nf = 2; nf < 4; ++nf) {
        acc[4 + mf][nf] = MFMA16(a47[mf][0], bb[nf][0], acc[4 + mf][nf]);
        acc[4 + mf][nf] = MFMA16(a47[mf][1], bb[nf][1], acc[4 + mf][nf]);
      }
    __builtin_amdgcn_s_setprio(0);
    if (T < NT - 2)
      asm volatile("s_waitcnt vmcnt(4)" ::: "memory");  // tile T+1 fully retired
    else if (T == NT - 2)
      asm volatile("s_waitcnt vmcnt(0)" ::: "memory");
    asm volatile("s_barrier" ::: "memory");
  }
#undef STG

  // ---- epilogue ----
#pragma unroll
  for (int mf = 0; mf < 8; ++mf) {
#pragma unroll
    for (int nf = 0; nf < 4; ++nf) {
      const int col = n0 + wn * 64 + nf * 16 + lr;
#pragma unroll
      for (int j = 0; j < 4; ++j) {
        const int row = m0 + wm * 128 + mf * 16 + g * 4 + j;
        const float v = acc[mf][nf][j];
        if (MODE == 0) {
          const int which = col >> 10, rr = col & 1023;
          const int h = rr >> 6, hd = rr & 63;
          const int bb_ = row >> 11, s = row & 2047;
          const size_t bh = (size_t)bb_ * 16 + h;
          if (which == 0)      q_o[(bh * 2048 + s) * 64 + hd] = f2bf(v * 0.125f);
          else if (which == 1) k_o[(bh * 2048 + s) * 64 + hd] = f2bf(v);
          else                 vt_o[(bh * 64 + hd) * 2048 + s] = f2bf(v);
        } else {
          f_o[(size_t)row * N + col] = v;
        }
      }
    }
  }
}

// ---------- 128x128 GEMM (proj): C[M][N] f32 = A * BT^T ----------
__global__ __launch_bounds__(256, 2)
void gemm_bt(const u16* __restrict__ A, const u16* __restrict__ BT,
             int K, int N, float* __restrict__ f_o) {
  __shared__ u16 As[128 * 32];
  __shared__ u16 Bs[128 * 32];
  const int t = threadIdx.x;
  const int w = t >> 6, l = t & 63;
  const int lr = l & 15, lk = (l >> 4) * 8;
  const int m0 = blockIdx.x * 128, n0 = blockIdx.y * 128;
  const int wr = (w >> 1) * 64, wc = (w & 1) * 64;
  f32x4 acc[4][4] = {};
  const int row_s = t >> 2, seg_s = (t & 3) * 8;

  for (int kk = 0; kk < K; kk += 32) {
    async_copy16(&As[t * 8],         &A[(size_t)(m0 + row_s) * K + kk + seg_s]);
    async_copy16(&As[(t + 256) * 8], &A[(size_t)(m0 + row_s + 64) * K + kk + seg_s]);
    async_copy16(&Bs[t * 8],         &BT[(size_t)(n0 + row_s) * K + kk + seg_s]);
    async_copy16(&Bs[(t + 256) * 8], &BT[(size_t)(n0 + row_s + 64) * K + kk + seg_s]);
    __syncthreads();
    bf16x8 af[4], bfr[4];
#pragma unroll
    for (int mf = 0; mf < 4; ++mf)
      af[mf] = *(const bf16x8*)&As[(wr + mf * 16 + lr) * 32 + lk];
#pragma unroll
    for (int nf = 0; nf < 4; ++nf)
      bfr[nf] = *(const bf16x8*)&Bs[(wc + nf * 16 + lr) * 32 + lk];
#pragma unroll
    for (int mf = 0; mf < 4; ++mf)
#pragma unroll
      for (int nf = 0; nf < 4; ++nf)
        acc[mf][nf] = MFMA16(af[mf], bfr[nf], acc[mf][nf]);
    __syncthreads();
  }

#pragma unroll
  for (int mf = 0; mf < 4; ++mf)
#pragma unroll
    for (int nf = 0; nf < 4; ++nf) {
      const int col = n0 + wc + nf * 16 + lr;
#pragma unroll
      for (int j = 0; j < 4; ++j) {
        const int row = m0 + wr + mf * 16 + ((l >> 4) << 2) + j;
        f_o[(size_t)row * N + col] = acc[mf][nf][j];
      }
    }
}

// ---------- flash attention (v3, unchanged from round 4) ----------
__global__ __launch_bounds__(256, 2)
void attn_kernel(const u16* __restrict__ qws, const u16* __restrict__ kws,
                 const u16* __restrict__ vtws, u16* __restrict__ ybf) {
  __shared__ u16 Ksh[2][64 * 64];
  __shared__ u16 VTsh[2][64 * 64];
  __shared__ u16 Psh[4][32 * 64];

  const int bh = blockIdx.x & 63;
  const int qtile = 15 - (blockIdx.x >> 6);
  const int t = threadIdx.x;
  const int w = t >> 6, l = t & 63;
  const int lr = l & 15, g = l >> 4;
  const int q0 = qtile * 128 + w * 32;

  bf16x8 qf[2][2];
#pragma unroll
  for (int mf = 0; mf < 2; ++mf) {
    const u16* qb = qws + ((size_t)bh * 2048 + q0 + mf * 16 + lr) * 64 + g * 8;
#pragma unroll
    for (int ks = 0; ks < 2; ++ks) qf[mf][ks] = *(const bf16x8*)(qb + ks * 32);
  }

  f32x4 oacc[2][4] = {};
  float lrun[2][4] = {};

  const int srow = t >> 3;
  const int ssw = ((t & 7) * 16) ^ ((srow & 7) << 4);
  const u16* kb0 = kws + ((size_t)bh * 2048 + srow) * 64 + (ssw >> 1);
  const u16* vb0 = vtws + ((size_t)bh * 64 + srow) * 2048 + (ssw >> 1);

#define STAGE(kv0, buf)                                                \
  do {                                                                 \
    async_copy16(&Ksh[buf][t * 8],          kb0 + (size_t)(kv0)*64);   \
    async_copy16(&Ksh[buf][(t + 256) * 8],  kb0 + (size_t)((kv0)+32)*64); \
    async_copy16(&VTsh[buf][t * 8],         vb0 + (kv0));              \
    async_copy16(&VTsh[buf][(t + 256) * 8], vb0 + (size_t)32*2048 + (kv0)); \
  } while (0)

  const int nt = (qtile + 1) * 2;
  STAGE(0, 0);
  __syncthreads();

  for (int ti = 0; ti < nt; ++ti) {
    const int kv0 = ti * 64;
    const int cur = ti & 1;
    if (ti + 1 < nt) STAGE((ti + 1) * 64, cur ^ 1);

    if (kv0 <= q0 + 31) {
      const u16* Kc = Ksh[cur];
      const u16* Vc = VTsh[cur];

      f32x4 s[2][4] = {};
      __builtin_amdgcn_s_setprio(1);
#pragma unroll
      for (int f = 0; f < 4; ++f) {
        const int krow = f * 16 + lr;
        const int kswz = (krow & 7) << 4;
#pragma unroll
        for (int ks = 0; ks < 2; ++ks) {
          bf16x8 kb = *(const bf16x8*)&Kc[krow * 64 + (((ks * 64 + g * 16) ^ kswz) >> 1)];
          s[0][f] = MFMA16(qf[0][ks], kb, s[0][f]);
          s[1][f] = MFMA16(qf[1][ks], kb, s[1][f]);
        }
      }
      __builtin_amdgcn_s_setprio(0);

      const bool diag = (kv0 + 63 > q0);
#pragma unroll
      for (int mf = 0; mf < 2; ++mf)
#pragma unroll
        for (int f = 0; f < 4; ++f)
#pragma unroll
          for (int j = 0; j < 4; ++j) {
            float p = __expf(s[mf][f][j]);
            if (diag) {
              const int key = kv0 + f * 16 + lr;
              const int qrow = q0 + mf * 16 + g * 4 + j;
              p = (key <= qrow) ? p : 0.f;
            }
            s[mf][f][j] = p;
            lrun[mf][j] += p;
          }

#pragma unroll
      for (int mf = 0; mf < 2; ++mf)
#pragma unroll
        for (int f = 0; f < 4; ++f)
#pragma unroll
          for (int j = 0; j < 4; ++j) {
            const int prow = mf * 16 + g * 4 + j;
            Psh[w][prow * 64 + (((f * 32 + lr * 2) ^ ((prow & 7) << 4)) >> 1)] =
                f2bf(s[mf][f][j]);
          }

#pragma unroll
      for (int ks = 0; ks < 2; ++ks) {
        bf16x8 pa[2];
#pragma unroll
        for (int mf = 0; mf < 2; ++mf) {
          const int prow = mf * 16 + lr;
          pa[mf] = *(const bf16x8*)&Psh[w][prow * 64 + (((ks * 64 + g * 16) ^ ((prow & 7) << 4)) >> 1)];
        }
        __builtin_amdgcn_s_setprio(1);
#pragma unroll
        for (int nf = 0; nf < 4; ++nf) {
          const int vrow = nf * 16 + lr;
          bf16x8 vb = *(const bf16x8*)&Vc[vrow * 64 + (((ks * 64 + g * 16) ^ ((vrow & 7) << 4)) >> 1)];
          oacc[0][nf] = MFMA16(pa[0], vb, oacc[0][nf]);
          oacc[1][nf] = MFMA16(pa[1], vb, oacc[1][nf]);
        }
        __builtin_amdgcn_s_setprio(0);
      }
    }
    __syncthreads();
  }
#undef STAGE

  float linv[2][4];
#pragma unroll
  for (int mf = 0; mf < 2; ++mf)
#pragma unroll
    for (int j = 0; j < 4; ++j) {
      float s = lrun[mf][j];
#pragma unroll
      for (int d = 1; d < 16; d <<= 1) s += __shfl_xor(s, d, 64);
      linv[mf][j] = 1.f / s;
    }

  const int b = bh >> 4, h = bh & 15;
#pragma unroll
  for (int mf = 0; mf < 2; ++mf)
#pragma unroll
    for (int nf = 0; nf < 4; ++nf) {
      const int col = nf * 16 + lr;
#pragma unroll
      for (int j = 0; j < 4; ++j) {
        const int row = q0 + mf * 16 + g * 4 + j;
        const float o = oacc[mf][nf][j] * linv[mf][j];
        ybf[((size_t)b * 2048 + row) * 1024 + h * 64 + col] = f2bf(o);
      }
    }
}

// ---------- launch ----------
extern "C" void kernel_launch(void* const* d_in, const int* in_sizes, int n_in,
                              void* d_out, int out_size, void* d_ws, size_t ws_size,
                              hipStream_t stream) {
  const float* x     = (const float*)d_in[0];   // [4,2048,1024]
  const float* wqkv  = (const float*)d_in[1];   // [1024,3072]
  const float* wproj = (const float*)d_in[2];   // [1024,1024]
  float* out = (float*)d_out;                   // [4,2048,1024] f32

  char* ws = (char*)d_ws;
  u16* xbf    = (u16*)ws;
  u16* ybf    = xbf;  // alias (x dead after qkv GEMM)
  u16* wqkvT  = (u16*)(ws + 16777216);
  u16* wprojT = (u16*)(ws + 16777216 + 6291456);
  u16* qws    = (u16*)(ws + 25165824);
  u16* kws    = (u16*)(ws + 41943040);
  u16* vtws   = (u16*)(ws + 58720256);

  cvt_bf16_kernel<<<2048, 256, 0, stream>>>(x, xbf, (8192 * 1024) / 4);
  transpose_cvt_kernel<<<dim3(3072 / 32, 1024 / 32), 256, 0, stream>>>(wqkv, wqkvT, 1024, 3072);
  transpose_cvt_kernel<<<dim3(1024 / 32, 1024 / 32), 256, 0, stream>>>(wproj, wprojT, 1024, 1024);
  // qkv GEMM: M=8192 N=3072 K=1024, 256x256 8-phase, scatter epilogue
  gemm256<0><<<dim3(32, 12), 512, 0, stream>>>(xbf, wqkvT, 3072, qws, kws, vtws, nullptr);
  attn_kernel<<<16 * 64, 256, 0, stream>>>(qws, kws, vtws, ybf);
  gemm_bt<<<dim3(64, 8), 256, 0, stream>>>(ybf, wprojT, 1024, 1024, out);
}

// Round 6
// 183.064 us; speedup vs baseline: 1.0755x; 1.0755x over previous
//
#include <hip/hip_runtime.h>
#include <stdint.h>

typedef unsigned short u16;
typedef __attribute__((ext_vector_type(8))) short bf16x8;
typedef __attribute__((ext_vector_type(4))) float f32x4;

// ---------- helpers ----------
__device__ __forceinline__ u16 f2bf(float f) {
  union { float f; unsigned u; } v; v.f = f;
  unsigned r = v.u + 0x7fffu + ((v.u >> 16) & 1u);  // round-to-nearest-even
  return (u16)(r >> 16);
}

__device__ __forceinline__ void async_copy16(u16* lds_dst, const u16* g_src) {
  __builtin_amdgcn_global_load_lds(
      (const __attribute__((address_space(1))) unsigned*)(g_src),
      (__attribute__((address_space(3))) unsigned*)(lds_dst),
      16, 0, 0);
}

#define MFMA16(a, b, c) __builtin_amdgcn_mfma_f32_16x16x32_bf16((a), (b), (c), 0, 0, 0)

// ---------- convert f32 -> bf16 (vectorized) ----------
__global__ void cvt_bf16_kernel(const float* __restrict__ in, u16* __restrict__ out, int n4) {
  int i = blockIdx.x * blockDim.x + threadIdx.x;
  int stride = gridDim.x * blockDim.x;
  for (; i < n4; i += stride) {
    float4 v = ((const float4*)in)[i];
    ushort4 o;
    o.x = f2bf(v.x); o.y = f2bf(v.y); o.z = f2bf(v.z); o.w = f2bf(v.w);
    ((ushort4*)out)[i] = o;
  }
}

// ---------- tiled transpose + convert: in [R][C] f32 -> out [C][R] bf16 ----------
__global__ void transpose_cvt_kernel(const float* __restrict__ in, u16* __restrict__ out,
                                     int R, int C) {
  __shared__ float tile[32][33];
  int bx = blockIdx.x * 32;
  int by = blockIdx.y * 32;
  int tx = threadIdx.x & 31, ty = threadIdx.x >> 5;
#pragma unroll
  for (int j = 0; j < 32; j += 8)
    tile[ty + j][tx] = in[(size_t)(by + ty + j) * C + bx + tx];
  __syncthreads();
#pragma unroll
  for (int j = 0; j < 32; j += 8)
    out[(size_t)(bx + ty + j) * R + by + tx] = f2bf(tile[tx][ty + j]);
}

// ---------- 2-phase 128x128 GEMM: C = A[M][K] * BT[N][K]^T ----------
// T3-minimum recipe (m230): full LDS double-buffer, STAGE(T+1) issued BEFORE
// compute of T, ONE barrier per K-tile (its implicit vmcnt/lgkm drain retires
// the stage). BK=64; LDS 64KB -> 2 blocks/CU. XOR-swizzle (row&7)<<4 via
// pre-swizzled global source; swizzled frag reads (2-way conflict = free).
// 256 thr = 4 waves (2x2), wave tile 64x64, acc 4x4.
// MODE 0: qkv scatter epilogue (q*0.125, k, vT bf16); MODE 1: f32 [M][N].
template<int MODE>
__global__ __launch_bounds__(256, 2)
void gemm2ph(const u16* __restrict__ A, const u16* __restrict__ BT,
             int K, int N,
             u16* __restrict__ q_o, u16* __restrict__ k_o, u16* __restrict__ vt_o,
             float* __restrict__ f_o) {
  __shared__ u16 As[2][128 * 64];  // [dbuf][row][64] rows=128B, swizzled
  __shared__ u16 Bs[2][128 * 64];

  const int t = threadIdx.x;
  const int w = t >> 6, l = t & 63;
  const int lr = l & 15, g = l >> 4;
  const int wm = (w >> 1) * 64, wn = (w & 1) * 64;
  const int m0 = blockIdx.x * 128, n0 = blockIdx.y * 128;

  // staging: load i in 0..3 covers row i*32 + (t>>3), byte-seg (t&7)*16.
  // LDS dst byte = i*4096 + t*16 (linear in lane, as global_load_lds needs);
  // global source col pre-swizzled so a swizzled READ returns plain data.
  const int r = t >> 3;
  const int sw = ((t & 7) * 16) ^ ((r & 7) << 4);
  const u16* pA = A + (size_t)(m0 + r) * K + (sw >> 1);
  const u16* pB = BT + (size_t)(n0 + r) * K + (sw >> 1);

#define STG(buf, kk)                                                    \
  do {                                                                  \
    async_copy16(&As[buf][t * 8],        pA + (kk));                    \
    async_copy16(&As[buf][2048 + t * 8], pA + (size_t)32 * K + (kk));   \
    async_copy16(&As[buf][4096 + t * 8], pA + (size_t)64 * K + (kk));   \
    async_copy16(&As[buf][6144 + t * 8], pA + (size_t)96 * K + (kk));   \
    async_copy16(&Bs[buf][t * 8],        pB + (kk));                    \
    async_copy16(&Bs[buf][2048 + t * 8], pB + (size_t)32 * K + (kk));   \
    async_copy16(&Bs[buf][4096 + t * 8], pB + (size_t)64 * K + (kk));   \
    async_copy16(&Bs[buf][6144 + t * 8], pB + (size_t)96 * K + (kk));   \
  } while (0)

  f32x4 acc[4][4] = {};

  STG(0, 0);
  __syncthreads();  // drain prologue stage

  const int NTt = K / 64;
  for (int T = 0; T < NTt; ++T) {
    const int cur = T & 1;
    if (T + 1 < NTt) STG(cur ^ 1, (T + 1) * 64);  // issue next-tile loads first

    bf16x8 af[4][2], bfr[4][2];
#pragma unroll
    for (int mf = 0; mf < 4; ++mf)
#pragma unroll
      for (int ks = 0; ks < 2; ++ks) {
        const int row = wm + mf * 16 + lr;
        af[mf][ks] = *(const bf16x8*)&As[cur][row * 64 + (((ks * 64 + g * 16) ^ ((row & 7) << 4)) >> 1)];
      }
#pragma unroll
    for (int nf = 0; nf < 4; ++nf)
#pragma unroll
      for (int ks = 0; ks < 2; ++ks) {
        const int row = wn + nf * 16 + lr;
        bfr[nf][ks] = *(const bf16x8*)&Bs[cur][row * 64 + (((ks * 64 + g * 16) ^ ((row & 7) << 4)) >> 1)];
      }
#pragma unroll
    for (int mf = 0; mf < 4; ++mf)
#pragma unroll
      for (int nf = 0; nf < 4; ++nf) {
        acc[mf][nf] = MFMA16(af[mf][0], bfr[nf][0], acc[mf][nf]);
        acc[mf][nf] = MFMA16(af[mf][1], bfr[nf][1], acc[mf][nf]);
      }
    __syncthreads();  // implicit vmcnt(0)+lgkm drain: next buf ready, reads done
  }
#undef STG

  // ---- epilogue ----
#pragma unroll
  for (int mf = 0; mf < 4; ++mf) {
#pragma unroll
    for (int nf = 0; nf < 4; ++nf) {
      const int col = n0 + wn + nf * 16 + lr;
#pragma unroll
      for (int j = 0; j < 4; ++j) {
        const int row = m0 + wm + mf * 16 + g * 4 + j;
        const float v = acc[mf][nf][j];
        if (MODE == 0) {
          const int which = col >> 10, rr = col & 1023;
          const int h = rr >> 6, hd = rr & 63;
          const int b = row >> 11, s = row & 2047;
          const size_t bh = (size_t)b * 16 + h;
          if (which == 0)      q_o[(bh * 2048 + s) * 64 + hd] = f2bf(v * 0.125f);
          else if (which == 1) k_o[(bh * 2048 + s) * 64 + hd] = f2bf(v);
          else                 vt_o[(bh * 64 + hd) * 2048 + s] = f2bf(v);
        } else {
          f_o[(size_t)row * N + col] = v;
        }
      }
    }
  }
}

// ---------- flash attention (v3, unchanged from round 4) ----------
__global__ __launch_bounds__(256, 2)
void attn_kernel(const u16* __restrict__ qws, const u16* __restrict__ kws,
                 const u16* __restrict__ vtws, u16* __restrict__ ybf) {
  __shared__ u16 Ksh[2][64 * 64];
  __shared__ u16 VTsh[2][64 * 64];
  __shared__ u16 Psh[4][32 * 64];

  const int bh = blockIdx.x & 63;
  const int qtile = 15 - (blockIdx.x >> 6);
  const int t = threadIdx.x;
  const int w = t >> 6, l = t & 63;
  const int lr = l & 15, g = l >> 4;
  const int q0 = qtile * 128 + w * 32;

  bf16x8 qf[2][2];
#pragma unroll
  for (int mf = 0; mf < 2; ++mf) {
    const u16* qb = qws + ((size_t)bh * 2048 + q0 + mf * 16 + lr) * 64 + g * 8;
#pragma unroll
    for (int ks = 0; ks < 2; ++ks) qf[mf][ks] = *(const bf16x8*)(qb + ks * 32);
  }

  f32x4 oacc[2][4] = {};
  float lrun[2][4] = {};

  const int srow = t >> 3;
  const int ssw = ((t & 7) * 16) ^ ((srow & 7) << 4);
  const u16* kb0 = kws + ((size_t)bh * 2048 + srow) * 64 + (ssw >> 1);
  const u16* vb0 = vtws + ((size_t)bh * 64 + srow) * 2048 + (ssw >> 1);

#define STAGE(kv0, buf)                                                \
  do {                                                                 \
    async_copy16(&Ksh[buf][t * 8],          kb0 + (size_t)(kv0)*64);   \
    async_copy16(&Ksh[buf][(t + 256) * 8],  kb0 + (size_t)((kv0)+32)*64); \
    async_copy16(&VTsh[buf][t * 8],         vb0 + (kv0));              \
    async_copy16(&VTsh[buf][(t + 256) * 8], vb0 + (size_t)32*2048 + (kv0)); \
  } while (0)

  const int nt = (qtile + 1) * 2;
  STAGE(0, 0);
  __syncthreads();

  for (int ti = 0; ti < nt; ++ti) {
    const int kv0 = ti * 64;
    const int cur = ti & 1;
    if (ti + 1 < nt) STAGE((ti + 1) * 64, cur ^ 1);

    if (kv0 <= q0 + 31) {
      const u16* Kc = Ksh[cur];
      const u16* Vc = VTsh[cur];

      f32x4 s[2][4] = {};
      __builtin_amdgcn_s_setprio(1);
#pragma unroll
      for (int f = 0; f < 4; ++f) {
        const int krow = f * 16 + lr;
        const int kswz = (krow & 7) << 4;
#pragma unroll
        for (int ks = 0; ks < 2; ++ks) {
          bf16x8 kb = *(const bf16x8*)&Kc[krow * 64 + (((ks * 64 + g * 16) ^ kswz) >> 1)];
          s[0][f] = MFMA16(qf[0][ks], kb, s[0][f]);
          s[1][f] = MFMA16(qf[1][ks], kb, s[1][f]);
        }
      }
      __builtin_amdgcn_s_setprio(0);

      const bool diag = (kv0 + 63 > q0);
#pragma unroll
      for (int mf = 0; mf < 2; ++mf)
#pragma unroll
        for (int f = 0; f < 4; ++f)
#pragma unroll
          for (int j = 0; j < 4; ++j) {
            float p = __expf(s[mf][f][j]);
            if (diag) {
              const int key = kv0 + f * 16 + lr;
              const int qrow = q0 + mf * 16 + g * 4 + j;
              p = (key <= qrow) ? p : 0.f;
            }
            s[mf][f][j] = p;
            lrun[mf][j] += p;
          }

#pragma unroll
      for (int mf = 0; mf < 2; ++mf)
#pragma unroll
        for (int f = 0; f < 4; ++f)
#pragma unroll
          for (int j = 0; j < 4; ++j) {
            const int prow = mf * 16 + g * 4 + j;
            Psh[w][prow * 64 + (((f * 32 + lr * 2) ^ ((prow & 7) << 4)) >> 1)] =
                f2bf(s[mf][f][j]);
          }

#pragma unroll
      for (int ks = 0; ks < 2; ++ks) {
        bf16x8 pa[2];
#pragma unroll
        for (int mf = 0; mf < 2; ++mf) {
          const int prow = mf * 16 + lr;
          pa[mf] = *(const bf16x8*)&Psh[w][prow * 64 + (((ks * 64 + g * 16) ^ ((prow & 7) << 4)) >> 1)];
        }
        __builtin_amdgcn_s_setprio(1);
#pragma unroll
        for (int nf = 0; nf < 4; ++nf) {
          const int vrow = nf * 16 + lr;
          bf16x8 vb = *(const bf16x8*)&Vc[vrow * 64 + (((ks * 64 + g * 16) ^ ((vrow & 7) << 4)) >> 1)];
          oacc[0][nf] = MFMA16(pa[0], vb, oacc[0][nf]);
          oacc[1][nf] = MFMA16(pa[1], vb, oacc[1][nf]);
        }
        __builtin_amdgcn_s_setprio(0);
      }
    }
    __syncthreads();
  }
#undef STAGE

  float linv[2][4];
#pragma unroll
  for (int mf = 0; mf < 2; ++mf)
#pragma unroll
    for (int j = 0; j < 4; ++j) {
      float s = lrun[mf][j];
#pragma unroll
      for (int d = 1; d < 16; d <<= 1) s += __shfl_xor(s, d, 64);
      linv[mf][j] = 1.f / s;
    }

  const int b = bh >> 4, h = bh & 15;
#pragma unroll
  for (int mf = 0; mf < 2; ++mf)
#pragma unroll
    for (int nf = 0; nf < 4; ++nf) {
      const int col = nf * 16 + lr;
#pragma unroll
      for (int j = 0; j < 4; ++j) {
        const int row = q0 + mf * 16 + g * 4 + j;
        const float o = oacc[mf][nf][j] * linv[mf][j];
        ybf[((size_t)b * 2048 + row) * 1024 + h * 64 + col] = f2bf(o);
      }
    }
}

// ---------- launch ----------
extern "C" void kernel_launch(void* const* d_in, const int* in_sizes, int n_in,
                              void* d_out, int out_size, void* d_ws, size_t ws_size,
                              hipStream_t stream) {
  const float* x     = (const float*)d_in[0];   // [4,2048,1024]
  const float* wqkv  = (const float*)d_in[1];   // [1024,3072]
  const float* wproj = (const float*)d_in[2];   // [1024,1024]
  float* out = (float*)d_out;                   // [4,2048,1024] f32

  char* ws = (char*)d_ws;
  u16* xbf    = (u16*)ws;
  u16* ybf    = xbf;  // alias (x dead after qkv GEMM)
  u16* wqkvT  = (u16*)(ws + 16777216);
  u16* wprojT = (u16*)(ws + 16777216 + 6291456);
  u16* qws    = (u16*)(ws + 25165824);
  u16* kws    = (u16*)(ws + 41943040);
  u16* vtws   = (u16*)(ws + 58720256);

  cvt_bf16_kernel<<<2048, 256, 0, stream>>>(x, xbf, (8192 * 1024) / 4);
  transpose_cvt_kernel<<<dim3(3072 / 32, 1024 / 32), 256, 0, stream>>>(wqkv, wqkvT, 1024, 3072);
  transpose_cvt_kernel<<<dim3(1024 / 32, 1024 / 32), 256, 0, stream>>>(wproj, wprojT, 1024, 1024);
  // qkv GEMM: M=8192 N=3072 K=1024 (1536 blocks = 3.0 occupancy waves)
  gemm2ph<0><<<dim3(64, 24), 256, 0, stream>>>(xbf, wqkvT, 1024, 3072, qws, kws, vtws, nullptr);
  attn_kernel<<<16 * 64, 256, 0, stream>>>(qws, kws, vtws, ybf);
  // proj GEMM: M=8192 N=1024 K=1024 (512 blocks = 1.0 occupancy wave)
  gemm2ph<1><<<dim3(64, 8), 256, 0, stream>>>(ybf, wprojT, 1024, 1024, nullptr, nullptr, nullptr, out);
}